// Round 4
// baseline (26008.441 us; speedup 1.0000x reference)
//
#include <hip/hip_runtime.h>
#include <hip/hip_fp16.h>

#define T_LEN 4096
#define HID   256
#define G4    1024

typedef unsigned int u32;
typedef _Float16 half2_t __attribute__((ext_vector_type(2)));

__device__ __forceinline__ float dot2f(u32 w, u32 h, float acc) {
#if __has_builtin(__builtin_amdgcn_fdot2)
    return __builtin_amdgcn_fdot2(__builtin_bit_cast(half2_t, w),
                                  __builtin_bit_cast(half2_t, h), acc, false);
#else
    __half2 wh = __builtin_bit_cast(__half2, w);
    __half2 hh = __builtin_bit_cast(__half2, h);
    float2 wf = __half22float2(wh), hf = __half22float2(hh);
    return acc + wf.x * hf.x + wf.y * hf.y;
#endif
}

__device__ __forceinline__ u32 pack2(float a, float b) {
    unsigned short lo = __half_as_ushort(__float2half(a));
    unsigned short hi = __half_as_ushort(__float2half(b));
    return ((u32)hi << 16) | (u32)lo;
}

// ---------------- transpose: out[k*N+n] = in[n*K+k] ----------------
__global__ void k_transpose(const float* __restrict__ in, float* __restrict__ out,
                            int N, int K) {
    int q = blockIdx.x * 256 + threadIdx.x;
    if (q >= N * K) return;
    int n = q / K, k = q % K;
    out[(size_t)k * N + n] = in[q];
}

// ---------------- pack Whh (1024x256 fp32) -> full reg-pack (f16x2) ----------
// Row->thread mapping matches k_scan: thread tid owns rows r0=tid, r1=tid+512.
// rp: [512 threads][256 u32]   j<128: row tid (all k), j>=128: row tid+512
__global__ void k_pack_whh(const float* __restrict__ W, u32* __restrict__ rp) {
    int q = blockIdx.x * 256 + threadIdx.x;
    if (q >= 512 * 256) return;
    int tid = q / 256, j = q % 256;
    int row = (j < 128) ? tid : tid + 512;
    int p = j & 127;
    rp[q] = pack2(W[row * 256 + 2 * p], W[row * 256 + 2 * p + 1]);
}

// ---------------- generic GEMM: C[M,N] = A[M,K] @ Wt[K,N] (+bias / relu / cosine)
// grid (M/16, N/256), block 256. mode: 0 bias, 1 bias+relu, 2 cosine epilogue
__global__ __launch_bounds__(256) void k_gemm(
    const float* __restrict__ A, const float* __restrict__ Wt,
    const float* __restrict__ bias, const float* __restrict__ norms,
    float* __restrict__ C, int M, int N, int K, int mode) {
    __shared__ float As[16 * 512];
    const int tid = threadIdx.x;
    const int m0 = blockIdx.x * 16;
    const int n  = blockIdx.y * 256 + tid;

    for (int i = tid; i < 16 * K; i += 256) As[i] = A[(size_t)m0 * K + i];
    __syncthreads();

    float acc[16];
#pragma unroll
    for (int m = 0; m < 16; ++m) acc[m] = 0.f;

#pragma unroll 4
    for (int k = 0; k < K; ++k) {
        float w = Wt[(size_t)k * N + n];
#pragma unroll
        for (int m = 0; m < 16; ++m) acc[m] += As[m * K + k] * w;
    }

    float bn = bias ? bias[n] : 0.f;
#pragma unroll
    for (int m = 0; m < 16; ++m) {
        float v = acc[m] + bn;
        if (mode == 1) v = fmaxf(v, 0.f);
        if (mode == 2) {
            float d = norms[m0 + m] * norms[n];
            v = 1.f - fmaxf(acc[m] / d, 1e-6f);
        }
        C[(size_t)(m0 + m) * N + n] = v;
    }
}

// ---------------- row norms of e (4096 x 256) ----------------
__global__ void k_norms(const float* __restrict__ e, float* __restrict__ norms) {
    int i = blockIdx.x, lane = threadIdx.x;
    float s = 0.f;
    for (int k = lane; k < 256; k += 64) { float v = e[i * 256 + k]; s += v * v; }
    for (int off = 32; off; off >>= 1) s += __shfl_down(s, off);
    if (lane == 0) norms[i] = sqrtf(s);
}

// ---------------- the recurrent scan: one block per direction ----------------
// xs: [2][T][1024] precomputed x@Wih.T + b (dir-major)
// rp: [2][512*256]  (all Whh weights register-resident, f16x2 packed)
// hout: [T][512], direction d writes columns d*256 .. d*256+255
//
// Round-0 structure (measured best): thread tid owns rows r0=tid, r1=tid+512.
//   tid<256:  a0 = z_i[tid], a1 = z_g[tid]
//   tid>=256: a0 = z_f[tid-256], a1 = z_o[tid-256]  -> exchanged via zsh LDS
// Two __syncthreads per step. ALL 256 weight u32/thread in registers (AGPRs);
// no LDS weight reads at all.
__global__ __launch_bounds__(512, 2) void k_scan(
    const float* __restrict__ xs, const u32* __restrict__ rp,
    float* __restrict__ hout) {
    __shared__ alignas(16) u32 hlds[128];       // 256 f16 packed hidden state
    __shared__ float zsh[512];                  // f,o gate exchange

    const int tid = threadIdx.x;
    const int dir = blockIdx.x;
    xs += (size_t)dir * (T_LEN * G4);
    rp += (size_t)dir * (512 * 256);

    if (tid < 128) hlds[tid] = 0u;

    u32 regw[256];
    {
        const uint4* rp4 = (const uint4*)(rp + (size_t)tid * 256);
#pragma unroll
        for (int p = 0; p < 64; ++p) {
            uint4 v = rp4[p];
            regw[4 * p + 0] = v.x; regw[4 * p + 1] = v.y;
            regw[4 * p + 2] = v.z; regw[4 * p + 3] = v.w;
        }
    }
    const int r0 = tid, r1 = tid + 512;
    float cst = 0.f;
    __syncthreads();

    int tt = dir ? (T_LEN - 1) : 0;
    float xn0 = xs[(size_t)tt * G4 + r0];
    float xn1 = xs[(size_t)tt * G4 + r1];

    for (int t = 0; t < T_LEN; ++t) {
        float a0 = xn0, a1 = xn1;
        int tn = dir ? ((t + 1 < T_LEN) ? T_LEN - 2 - t : 0)
                     : ((t + 1 < T_LEN) ? t + 1 : T_LEN - 1);
        xn0 = xs[(size_t)tn * G4 + r0];   // prefetch next step
        xn1 = xs[(size_t)tn * G4 + r1];

        // all 256 k's from register weights, h broadcast from LDS (4 clusters)
#pragma unroll
        for (int c = 0; c < 4; ++c) {
            u32 hh[32];
#pragma unroll
            for (int q = 0; q < 8; ++q) {
                uint4 v = *(const uint4*)&hlds[c * 32 + 4 * q];
                hh[4 * q + 0] = v.x; hh[4 * q + 1] = v.y;
                hh[4 * q + 2] = v.z; hh[4 * q + 3] = v.w;
            }
#pragma unroll
            for (int p = 0; p < 32; ++p) {
                a0 = dot2f(regw[c * 32 + p],       hh[p], a0);
                a1 = dot2f(regw[128 + c * 32 + p], hh[p], a1);
            }
        }

        // rows: tid<256 -> a0=i[n],a1=g[n]; tid>=256 -> a0=f[n],a1=o[n]
        if (tid >= 256) { zsh[tid - 256] = a0; zsh[256 + (tid - 256)] = a1; }
        __syncthreads();
        if (tid < 256) {
            float zi = a0, zg = a1;
            float zf = zsh[tid], zo = zsh[256 + tid];
            float si = 1.f / (1.f + __expf(-zi));
            float sf = 1.f / (1.f + __expf(-zf));
            float so = 1.f / (1.f + __expf(-zo));
            float tg = 1.f - 2.f / (__expf(2.f * zg) + 1.f);
            cst = sf * cst + si * tg;
            float th = 1.f - 2.f / (__expf(2.f * cst) + 1.f);
            float hv = so * th;
            hout[(size_t)tt * 512 + dir * 256 + tid] = hv;
            ((__half*)hlds)[tid] = __float2half(hv);
        }
        __syncthreads();
        tt = tn;
    }
}

// ---------------- launcher ----------------
extern "C" void kernel_launch(void* const* d_in, const int* in_sizes, int n_in,
                              void* d_out, int out_size, void* d_ws, size_t ws_size,
                              hipStream_t stream) {
    const float* x       = (const float*)d_in[0];
    const float* wih_l0f = (const float*)d_in[1];
    const float* whh_l0f = (const float*)d_in[2];
    const float* b_l0f   = (const float*)d_in[3];
    const float* wih_l0b = (const float*)d_in[4];
    const float* whh_l0b = (const float*)d_in[5];
    const float* b_l0b   = (const float*)d_in[6];
    const float* wih_l1f = (const float*)d_in[7];
    const float* whh_l1f = (const float*)d_in[8];
    const float* b_l1f   = (const float*)d_in[9];
    const float* wih_l1b = (const float*)d_in[10];
    const float* whh_l1b = (const float*)d_in[11];
    const float* b_l1b   = (const float*)d_in[12];
    const float* fc1_w   = (const float*)d_in[13];
    const float* fc1_b   = (const float*)d_in[14];
    const float* fc2_w   = (const float*)d_in[15];
    const float* fc2_b   = (const float*)d_in[16];
    float* outp = (float*)d_out;

    char* ws = (char*)d_ws;
    size_t off = 0;
    auto alloc = [&](size_t nbytes) {
        char* p = ws + off;
        off += (nbytes + 255) & ~(size_t)255;
        return p;
    };
    float* xs0   = (float*)alloc((size_t)2 * T_LEN * G4 * 4);
    float* xs1   = (float*)alloc((size_t)2 * T_LEN * G4 * 4);
    float* h1    = (float*)alloc((size_t)T_LEN * 512 * 4);
    float* h2    = (float*)alloc((size_t)T_LEN * 512 * 4);
    float* zb    = (float*)alloc((size_t)T_LEN * 256 * 4);
    float* eb    = (float*)alloc((size_t)T_LEN * 256 * 4);
    float* etb   = (float*)alloc((size_t)T_LEN * 256 * 4);
    float* nrm   = (float*)alloc((size_t)T_LEN * 4);
    float* wt0f  = (float*)alloc((size_t)128 * 1024 * 4);
    float* wt0b  = (float*)alloc((size_t)128 * 1024 * 4);
    float* wt1f  = (float*)alloc((size_t)512 * 1024 * 4);
    float* wt1b  = (float*)alloc((size_t)512 * 1024 * 4);
    float* wtf1  = (float*)alloc((size_t)512 * 256 * 4);
    float* wtf2  = (float*)alloc((size_t)256 * 256 * 4);
    u32*   rp0   = (u32*)alloc((size_t)2 * 512 * 256 * 4);
    u32*   rp1   = (u32*)alloc((size_t)2 * 512 * 256 * 4);

    // weight transposes
    k_transpose<<<(1024 * 128 + 255) / 256, 256, 0, stream>>>(wih_l0f, wt0f, 1024, 128);
    k_transpose<<<(1024 * 128 + 255) / 256, 256, 0, stream>>>(wih_l0b, wt0b, 1024, 128);
    k_transpose<<<(1024 * 512 + 255) / 256, 256, 0, stream>>>(wih_l1f, wt1f, 1024, 512);
    k_transpose<<<(1024 * 512 + 255) / 256, 256, 0, stream>>>(wih_l1b, wt1b, 1024, 512);
    k_transpose<<<(256 * 512 + 255) / 256, 256, 0, stream>>>(fc1_w, wtf1, 256, 512);
    k_transpose<<<(256 * 256 + 255) / 256, 256, 0, stream>>>(fc2_w, wtf2, 256, 256);

    // recurrent weight packs (full register pack)
    const int packN = (512 * 256 + 255) / 256;
    k_pack_whh<<<packN, 256, 0, stream>>>(whh_l0f, rp0);
    k_pack_whh<<<packN, 256, 0, stream>>>(whh_l0b, rp0 + 512 * 256);
    k_pack_whh<<<packN, 256, 0, stream>>>(whh_l1f, rp1);
    k_pack_whh<<<packN, 256, 0, stream>>>(whh_l1b, rp1 + 512 * 256);

    dim3 g1024(T_LEN / 16, 4);
    // layer 0 input projections
    k_gemm<<<g1024, 256, 0, stream>>>(x, wt0f, b_l0f, nullptr, xs0, T_LEN, 1024, 128, 0);
    k_gemm<<<g1024, 256, 0, stream>>>(x, wt0b, b_l0b, nullptr, xs0 + (size_t)T_LEN * G4, T_LEN, 1024, 128, 0);
    // layer 0 scan (both directions)
    k_scan<<<2, 512, 0, stream>>>(xs0, rp0, h1);
    // layer 1 input projections
    k_gemm<<<g1024, 256, 0, stream>>>(h1, wt1f, b_l1f, nullptr, xs1, T_LEN, 1024, 512, 0);
    k_gemm<<<g1024, 256, 0, stream>>>(h1, wt1b, b_l1b, nullptr, xs1 + (size_t)T_LEN * G4, T_LEN, 1024, 512, 0);
    // layer 1 scan
    k_scan<<<2, 512, 0, stream>>>(xs1, rp1, h2);
    // FC head
    k_gemm<<<dim3(T_LEN / 16, 1), 256, 0, stream>>>(h2, wtf1, fc1_b, nullptr, zb, T_LEN, 256, 512, 1);
    k_gemm<<<dim3(T_LEN / 16, 1), 256, 0, stream>>>(zb, wtf2, fc2_b, nullptr, eb, T_LEN, 256, 256, 0);
    // cosine-similarity output
    k_transpose<<<(T_LEN * 256 + 255) / 256, 256, 0, stream>>>(eb, etb, T_LEN, 256);
    k_norms<<<T_LEN, 64, 0, stream>>>(eb, nrm);
    k_gemm<<<dim3(T_LEN / 16, T_LEN / 256), 256, 0, stream>>>(eb, etb, nullptr, nrm, outp, T_LEN, T_LEN, 256, 2);
}

// Round 5
// 23286.108 us; speedup vs baseline: 1.1169x; 1.1169x over previous
//
#include <hip/hip_runtime.h>
#include <hip/hip_fp16.h>

#define T_LEN 4096
#define HID   256
#define G4    1024
#define NSL   4            // slices per direction
#define DIRSZ (NSL * 256 * 128)   // packed weight u32 per direction

typedef unsigned int u32;
typedef _Float16 half2_t __attribute__((ext_vector_type(2)));

__device__ __forceinline__ float dot2f(u32 w, u32 h, float acc) {
#if __has_builtin(__builtin_amdgcn_fdot2)
    return __builtin_amdgcn_fdot2(__builtin_bit_cast(half2_t, w),
                                  __builtin_bit_cast(half2_t, h), acc, false);
#else
    __half2 wh = __builtin_bit_cast(__half2, w);
    __half2 hh = __builtin_bit_cast(__half2, h);
    float2 wf = __half22float2(wh), hf = __half22float2(hh);
    return acc + wf.x * hf.x + wf.y * hf.y;
#endif
}

__device__ __forceinline__ u32 pack2(float a, float b) {
    unsigned short lo = __half_as_ushort(__float2half(a));
    unsigned short hi = __half_as_ushort(__float2half(b));
    return ((u32)hi << 16) | (u32)lo;
}

// ---------------- zero helper (flags must be 0 at each launch) ----------------
__global__ void k_zero(u32* __restrict__ p, int n) {
    int q = blockIdx.x * 256 + threadIdx.x;
    if (q < n) p[q] = 0u;
}

// ---------------- transpose: out[k*N+n] = in[n*K+k] ----------------
__global__ void k_transpose(const float* __restrict__ in, float* __restrict__ out,
                            int N, int K) {
    int q = blockIdx.x * 256 + threadIdx.x;
    if (q >= N * K) return;
    int n = q / K, k = q % K;
    out[(size_t)k * N + n] = in[q];
}

// ---------------- pack Whh (1024x256 fp32) -> per-slice reg pack (f16x2) -----
// Scan thread (slice s, tid j) owns row = (j>>6)*256 + s*64 + (j&63) and reads
// rp[(s*256+j)*128 + p] = pack(W[row][2p], W[row][2p+1]).
__global__ void k_pack_whh_mc(const float* __restrict__ W, u32* __restrict__ out) {
    int q = blockIdx.x * 256 + threadIdx.x;     // 4*256*128 = 131072 total
    if (q >= NSL * 256 * 128) return;
    int p = q & 127;
    int j = (q >> 7) & 255;
    int s = q >> 15;
    int row = ((j >> 6) * 256) + s * 64 + (j & 63);
    out[q] = pack2(W[row * 256 + 2 * p], W[row * 256 + 2 * p + 1]);
}

// ---------------- generic GEMM: C[M,N] = A[M,K] @ Wt[K,N] (+bias/relu/cosine)
__global__ __launch_bounds__(256) void k_gemm(
    const float* __restrict__ A, const float* __restrict__ Wt,
    const float* __restrict__ bias, const float* __restrict__ norms,
    float* __restrict__ C, int M, int N, int K, int mode) {
    __shared__ float As[16 * 512];
    const int tid = threadIdx.x;
    const int m0 = blockIdx.x * 16;
    const int n  = blockIdx.y * 256 + tid;

    for (int i = tid; i < 16 * K; i += 256) As[i] = A[(size_t)m0 * K + i];
    __syncthreads();

    float acc[16];
#pragma unroll
    for (int m = 0; m < 16; ++m) acc[m] = 0.f;

#pragma unroll 4
    for (int k = 0; k < K; ++k) {
        float w = Wt[(size_t)k * N + n];
#pragma unroll
        for (int m = 0; m < 16; ++m) acc[m] += As[m * K + k] * w;
    }

    float bn = bias ? bias[n] : 0.f;
#pragma unroll
    for (int m = 0; m < 16; ++m) {
        float v = acc[m] + bn;
        if (mode == 1) v = fmaxf(v, 0.f);
        if (mode == 2) {
            float d = norms[m0 + m] * norms[n];
            v = 1.f - fmaxf(acc[m] / d, 1e-6f);
        }
        C[(size_t)(m0 + m) * N + n] = v;
    }
}

// ---------------- row norms of e (4096 x 256) ----------------
__global__ void k_norms(const float* __restrict__ e, float* __restrict__ norms) {
    int i = blockIdx.x, lane = threadIdx.x;
    float s = 0.f;
    for (int k = lane; k < 256; k += 64) { float v = e[i * 256 + k]; s += v * v; }
    for (int off = 32; off; off >>= 1) s += __shfl_down(s, off);
    if (lane == 0) norms[i] = sqrtf(s);
}

// ---------------- multi-CU recurrent scan ----------------
// Grid: 8 blocks = 2 dirs x 4 slices (dir = bid>>2, s = bid&3), 256 thr/block.
// Slice s owns hidden units n in [64s, 64s+64): rows g*256 + 64s + u, g=0..3.
// Thread j: row = (j>>6)*256 + 64s + (j&63); 128 weight u32 in VGPRs.
// Per step: dot -> zex exchange -> 32 lanes do gate math for unit pairs ->
// publish 32-u32 h-chunk (relaxed agent atomics) + release flag ->
// poll 3 remote flags (acquire) -> gather 96 u32 into local h LDS.
// 8 blocks on 256 CUs are co-resident (persistent-kernel pattern).
__global__ __launch_bounds__(256, 1) void k_scan_mc(
    const float* __restrict__ xs, const u32* __restrict__ rp,
    u32* __restrict__ hx, u32* __restrict__ fl, float* __restrict__ hout) {
    __shared__ alignas(16) u32 hloc[128];    // full h(t-1), f16x2 packed
    __shared__ float zex[4][64];             // gate-major z exchange

    const int tid = threadIdx.x;
    const int dir = blockIdx.x >> 2;
    const int s   = blockIdx.x & 3;
    const int u_  = tid & 63;
    const int g   = tid >> 6;
    const int row = g * 256 + s * 64 + u_;

    xs += (size_t)dir * (T_LEN * G4);
    rp += (size_t)dir * DIRSZ;
    u32* hxd = hx + (size_t)dir * (T_LEN * 128);
    u32* fld = fl + dir * (NSL * 32);        // flags padded to 128B apart

    u32 regw[128];
    {
        const uint4* rp4 = (const uint4*)(rp + (size_t)(s * 256 + tid) * 128);
#pragma unroll
        for (int p = 0; p < 32; ++p) {
            uint4 v = rp4[p];
            regw[4 * p + 0] = v.x; regw[4 * p + 1] = v.y;
            regw[4 * p + 2] = v.z; regw[4 * p + 3] = v.w;
        }
    }
    if (tid < 128) hloc[tid] = 0u;
    float cst0 = 0.f, cst1 = 0.f;
    __syncthreads();

    int tt = dir ? (T_LEN - 1) : 0;
    const int stp = dir ? -1 : 1;
    float xa = xs[(size_t)tt * G4 + row];

    for (int t = 0; t < T_LEN; ++t) {
        float a = xa;
        int tn = (t + 1 < T_LEN) ? tt + stp : tt;
        xa = xs[(size_t)tn * G4 + row];      // prefetch next step

        // z[row] = xs + Whh[row,:] . h  (k ascending in f16 pairs, as before)
#pragma unroll
        for (int c = 0; c < 4; ++c) {
            u32 hh[32];
#pragma unroll
            for (int q = 0; q < 8; ++q) {
                uint4 v = *(const uint4*)&hloc[c * 32 + 4 * q];
                hh[4 * q + 0] = v.x; hh[4 * q + 1] = v.y;
                hh[4 * q + 2] = v.z; hh[4 * q + 3] = v.w;
            }
#pragma unroll
            for (int p = 0; p < 32; ++p)
                a = dot2f(regw[c * 32 + p], hh[p], a);
        }

        zex[g][u_] = a;
        __syncthreads();

        if (tid < 32) {                       // unit pair (64s+2*tid, +1)
            float zi0 = zex[0][2 * tid], zi1 = zex[0][2 * tid + 1];
            float zf0 = zex[1][2 * tid], zf1 = zex[1][2 * tid + 1];
            float zg0 = zex[2][2 * tid], zg1 = zex[2][2 * tid + 1];
            float zo0 = zex[3][2 * tid], zo1 = zex[3][2 * tid + 1];

            float si0 = 1.f / (1.f + __expf(-zi0));
            float sf0 = 1.f / (1.f + __expf(-zf0));
            float so0 = 1.f / (1.f + __expf(-zo0));
            float tg0 = 1.f - 2.f / (__expf(2.f * zg0) + 1.f);
            cst0 = sf0 * cst0 + si0 * tg0;
            float th0 = 1.f - 2.f / (__expf(2.f * cst0) + 1.f);
            float hv0 = so0 * th0;

            float si1 = 1.f / (1.f + __expf(-zi1));
            float sf1 = 1.f / (1.f + __expf(-zf1));
            float so1 = 1.f / (1.f + __expf(-zo1));
            float tg1 = 1.f - 2.f / (__expf(2.f * zg1) + 1.f);
            cst1 = sf1 * cst1 + si1 * tg1;
            float th1 = 1.f - 2.f / (__expf(2.f * cst1) + 1.f);
            float hv1 = so1 * th1;

            u32 hp = pack2(hv0, hv1);
            hloc[s * 32 + tid] = hp;          // own chunk locally
            __hip_atomic_store(&hxd[(size_t)t * 128 + s * 32 + tid], hp,
                               __ATOMIC_RELAXED, __HIP_MEMORY_SCOPE_AGENT);
            float2 hvv; hvv.x = hv0; hvv.y = hv1;
            *(float2*)&hout[(size_t)tt * 512 + dir * 256 + s * 64 + 2 * tid] = hvv;
        }
        __threadfence();                      // data visible before flag
        __syncthreads();
        if (tid == 0)
            __hip_atomic_store(&fld[s * 32], (u32)(t + 1),
                               __ATOMIC_RELEASE, __HIP_MEMORY_SCOPE_AGENT);

        if (tid < NSL && tid != s) {
            while (__hip_atomic_load(&fld[tid * 32], __ATOMIC_ACQUIRE,
                                     __HIP_MEMORY_SCOPE_AGENT) < (u32)(t + 1))
                __builtin_amdgcn_s_sleep(1);
        }
        __syncthreads();
        if (tid < 128 && (tid >> 5) != s)
            hloc[tid] = __hip_atomic_load(&hxd[(size_t)t * 128 + tid],
                                          __ATOMIC_RELAXED, __HIP_MEMORY_SCOPE_AGENT);
        __syncthreads();
        tt = tn;
    }
}

// ---------------- launcher ----------------
extern "C" void kernel_launch(void* const* d_in, const int* in_sizes, int n_in,
                              void* d_out, int out_size, void* d_ws, size_t ws_size,
                              hipStream_t stream) {
    const float* x       = (const float*)d_in[0];
    const float* wih_l0f = (const float*)d_in[1];
    const float* whh_l0f = (const float*)d_in[2];
    const float* b_l0f   = (const float*)d_in[3];
    const float* wih_l0b = (const float*)d_in[4];
    const float* whh_l0b = (const float*)d_in[5];
    const float* b_l0b   = (const float*)d_in[6];
    const float* wih_l1f = (const float*)d_in[7];
    const float* whh_l1f = (const float*)d_in[8];
    const float* b_l1f   = (const float*)d_in[9];
    const float* wih_l1b = (const float*)d_in[10];
    const float* whh_l1b = (const float*)d_in[11];
    const float* b_l1b   = (const float*)d_in[12];
    const float* fc1_w   = (const float*)d_in[13];
    const float* fc1_b   = (const float*)d_in[14];
    const float* fc2_w   = (const float*)d_in[15];
    const float* fc2_b   = (const float*)d_in[16];
    float* outp = (float*)d_out;

    char* ws = (char*)d_ws;
    size_t off = 0;
    auto alloc = [&](size_t nbytes) {
        char* p = ws + off;
        off += (nbytes + 255) & ~(size_t)255;
        return p;
    };
    float* xs0   = (float*)alloc((size_t)2 * T_LEN * G4 * 4);
    float* xs1   = (float*)alloc((size_t)2 * T_LEN * G4 * 4);
    float* h1    = (float*)alloc((size_t)T_LEN * 512 * 4);
    float* h2    = (float*)alloc((size_t)T_LEN * 512 * 4);
    float* zb    = (float*)alloc((size_t)T_LEN * 256 * 4);
    float* eb    = (float*)alloc((size_t)T_LEN * 256 * 4);
    float* etb   = (float*)alloc((size_t)T_LEN * 256 * 4);
    float* nrm   = (float*)alloc((size_t)T_LEN * 4);
    float* wt0f  = (float*)alloc((size_t)128 * 1024 * 4);
    float* wt0b  = (float*)alloc((size_t)128 * 1024 * 4);
    float* wt1f  = (float*)alloc((size_t)512 * 1024 * 4);
    float* wt1b  = (float*)alloc((size_t)512 * 1024 * 4);
    float* wtf1  = (float*)alloc((size_t)512 * 256 * 4);
    float* wtf2  = (float*)alloc((size_t)256 * 256 * 4);
    u32*   rpm0  = (u32*)alloc((size_t)2 * DIRSZ * 4);
    u32*   rpm1  = (u32*)alloc((size_t)2 * DIRSZ * 4);
    u32*   hx0   = (u32*)alloc((size_t)2 * T_LEN * 128 * 4);
    u32*   hx1   = (u32*)alloc((size_t)2 * T_LEN * 128 * 4);
    u32*   fl0   = (u32*)alloc((size_t)2 * NSL * 32 * 4);
    u32*   fl1   = (u32*)alloc((size_t)2 * NSL * 32 * 4);

    // reset sync flags (every launch / graph replay)
    k_zero<<<1, 256, 0, stream>>>(fl0, 2 * NSL * 32);
    k_zero<<<1, 256, 0, stream>>>(fl1, 2 * NSL * 32);

    // weight transposes
    k_transpose<<<(1024 * 128 + 255) / 256, 256, 0, stream>>>(wih_l0f, wt0f, 1024, 128);
    k_transpose<<<(1024 * 128 + 255) / 256, 256, 0, stream>>>(wih_l0b, wt0b, 1024, 128);
    k_transpose<<<(1024 * 512 + 255) / 256, 256, 0, stream>>>(wih_l1f, wt1f, 1024, 512);
    k_transpose<<<(1024 * 512 + 255) / 256, 256, 0, stream>>>(wih_l1b, wt1b, 1024, 512);
    k_transpose<<<(256 * 512 + 255) / 256, 256, 0, stream>>>(fc1_w, wtf1, 256, 512);
    k_transpose<<<(256 * 256 + 255) / 256, 256, 0, stream>>>(fc2_w, wtf2, 256, 256);

    // recurrent weight packs (per-slice row->thread mapping)
    k_pack_whh_mc<<<512, 256, 0, stream>>>(whh_l0f, rpm0);
    k_pack_whh_mc<<<512, 256, 0, stream>>>(whh_l0b, rpm0 + DIRSZ);
    k_pack_whh_mc<<<512, 256, 0, stream>>>(whh_l1f, rpm1);
    k_pack_whh_mc<<<512, 256, 0, stream>>>(whh_l1b, rpm1 + DIRSZ);

    dim3 g1024(T_LEN / 16, 4);
    // layer 0 input projections
    k_gemm<<<g1024, 256, 0, stream>>>(x, wt0f, b_l0f, nullptr, xs0, T_LEN, 1024, 128, 0);
    k_gemm<<<g1024, 256, 0, stream>>>(x, wt0b, b_l0b, nullptr, xs0 + (size_t)T_LEN * G4, T_LEN, 1024, 128, 0);
    // layer 0 scan (2 dirs x 4 slices)
    k_scan_mc<<<8, 256, 0, stream>>>(xs0, rpm0, hx0, fl0, h1);
    // layer 1 input projections
    k_gemm<<<g1024, 256, 0, stream>>>(h1, wt1f, b_l1f, nullptr, xs1, T_LEN, 1024, 512, 0);
    k_gemm<<<g1024, 256, 0, stream>>>(h1, wt1b, b_l1b, nullptr, xs1 + (size_t)T_LEN * G4, T_LEN, 1024, 512, 0);
    // layer 1 scan
    k_scan_mc<<<8, 256, 0, stream>>>(xs1, rpm1, hx1, fl1, h2);
    // FC head
    k_gemm<<<dim3(T_LEN / 16, 1), 256, 0, stream>>>(h2, wtf1, fc1_b, nullptr, zb, T_LEN, 256, 512, 1);
    k_gemm<<<dim3(T_LEN / 16, 1), 256, 0, stream>>>(zb, wtf2, fc2_b, nullptr, eb, T_LEN, 256, 256, 0);
    // cosine-similarity output
    k_transpose<<<(T_LEN * 256 + 255) / 256, 256, 0, stream>>>(eb, etb, T_LEN, 256);
    k_norms<<<T_LEN, 64, 0, stream>>>(eb, nrm);
    k_gemm<<<dim3(T_LEN / 16, T_LEN / 256), 256, 0, stream>>>(eb, etb, nullptr, nrm, outp, T_LEN, T_LEN, 256, 2);
}

// Round 6
// 13599.374 us; speedup vs baseline: 1.9125x; 1.7123x over previous
//
#include <hip/hip_runtime.h>
#include <hip/hip_fp16.h>

#define T_LEN 4096
#define HID   256
#define G4    1024
#define DIRSZ (1024 * 128)   // packed weight u32 per direction (1024 rows x 128 pairs)

typedef unsigned int u32;
typedef unsigned long long u64;
typedef _Float16 half2_t __attribute__((ext_vector_type(2)));

__device__ __forceinline__ float dot2f(u32 w, u32 h, float acc) {
#if __has_builtin(__builtin_amdgcn_fdot2)
    return __builtin_amdgcn_fdot2(__builtin_bit_cast(half2_t, w),
                                  __builtin_bit_cast(half2_t, h), acc, false);
#else
    __half2 wh = __builtin_bit_cast(__half2, w);
    __half2 hh = __builtin_bit_cast(__half2, h);
    float2 wf = __half22float2(wh), hf = __half22float2(hh);
    return acc + wf.x * hf.x + wf.y * hf.y;
#endif
}

__device__ __forceinline__ u32 pack2(float a, float b) {
    unsigned short lo = __half_as_ushort(__float2half(a));
    unsigned short hi = __half_as_ushort(__float2half(b));
    return ((u32)hi << 16) | (u32)lo;
}

// lgkm-only barrier: never drains vmcnt (global stores/loads keep flying)
__device__ __forceinline__ void step_barrier() {
    asm volatile("s_waitcnt lgkmcnt(0)" ::: "memory");
    __builtin_amdgcn_s_barrier();
    __builtin_amdgcn_sched_barrier(0);
}

// ---------------- zero helper (exchange tags must be 0 at each launch) -------
__global__ void k_zero(u32* __restrict__ p, int n) {
    int q = blockIdx.x * 256 + threadIdx.x;
    if (q < n) p[q] = 0u;
}

// ---------------- transpose: out[k*N+n] = in[n*K+k] ----------------
__global__ void k_transpose(const float* __restrict__ in, float* __restrict__ out,
                            int N, int K) {
    int q = blockIdx.x * 256 + threadIdx.x;
    if (q >= N * K) return;
    int n = q / K, k = q % K;
    out[(size_t)k * N + n] = in[q];
}

// ---------------- pack Whh (1024x256 fp32) -> per-slice reg pack (f16x2) -----
// Scan thread (slice s, tid j) owns row = (j>>7)*256 + s*128 + (j&127);
// rp[(s*512 + j)*128 + p] = pack(W[row][2p], W[row][2p+1]).
__global__ void k_pack_whh_mc(const float* __restrict__ W, u32* __restrict__ out) {
    int q = blockIdx.x * 256 + threadIdx.x;     // 1024*128 = 131072 total
    if (q >= 1024 * 128) return;
    int p = q & 127;
    int j = (q >> 7) & 511;
    int s = q >> 16;                            // 512*128 = 65536 per slice
    int row = ((j >> 7) * 256) + s * 128 + (j & 127);
    out[q] = pack2(W[row * 256 + 2 * p], W[row * 256 + 2 * p + 1]);
}

// ---------------- generic GEMM: C[M,N] = A[M,K] @ Wt[K,N] (+bias/relu/cosine)
__global__ __launch_bounds__(256) void k_gemm(
    const float* __restrict__ A, const float* __restrict__ Wt,
    const float* __restrict__ bias, const float* __restrict__ norms,
    float* __restrict__ C, int M, int N, int K, int mode) {
    __shared__ float As[16 * 512];
    const int tid = threadIdx.x;
    const int m0 = blockIdx.x * 16;
    const int n  = blockIdx.y * 256 + tid;

    for (int i = tid; i < 16 * K; i += 256) As[i] = A[(size_t)m0 * K + i];
    __syncthreads();

    float acc[16];
#pragma unroll
    for (int m = 0; m < 16; ++m) acc[m] = 0.f;

#pragma unroll 4
    for (int k = 0; k < K; ++k) {
        float w = Wt[(size_t)k * N + n];
#pragma unroll
        for (int m = 0; m < 16; ++m) acc[m] += As[m * K + k] * w;
    }

    float bn = bias ? bias[n] : 0.f;
#pragma unroll
    for (int m = 0; m < 16; ++m) {
        float v = acc[m] + bn;
        if (mode == 1) v = fmaxf(v, 0.f);
        if (mode == 2) {
            float d = norms[m0 + m] * norms[n];
            v = 1.f - fmaxf(acc[m] / d, 1e-6f);
        }
        C[(size_t)(m0 + m) * N + n] = v;
    }
}

// ---------------- row norms of e (4096 x 256) ----------------
__global__ void k_norms(const float* __restrict__ e, float* __restrict__ norms) {
    int i = blockIdx.x, lane = threadIdx.x;
    float s = 0.f;
    for (int k = lane; k < 256; k += 64) { float v = e[i * 256 + k]; s += v * v; }
    for (int off = 32; off; off >>= 1) s += __shfl_down(s, off);
    if (lane == 0) norms[i] = sqrtf(s);
}

// ---------------- 2-CU-per-direction recurrent scan ----------------
// Grid 16 blocks x 512 thr. Workers: bid in {0,1,8,9}: dir = bid&7, s = bid>>3.
// (bid%8 likely maps to XCD; 0,8 -> same XCD so dir-partners share an L2.
//  Placement is a heuristic only - correctness never depends on it.)
// Slice s owns units [128s,128s+128): thread (g=tid>>7, u=tid&127) owns row
// g*256 + s*128 + u with its 128 f16x2 weights in VGPRs.
//
// Cross-CU h exchange: tag+payload in ONE u64 (tag=t+1 | 2xf16 h), relaxed
// agent-scope store (fire-and-forget, NO fence, NO vmcnt drain). Consumer
// polls with acquire loads until tag==t+1: detect + data in one LLC trip.
// Slots double-buffered by t&1: overwrite needs producer 2 steps ahead, which
// transitively requires the consumer's prior read -> race-free.
// Per step: dots -> zex -> bar -> {wave0: gates+publish || wave1: poll} -> bar.
__global__ __launch_bounds__(512, 2) void k_scan_mc2(
    const float* __restrict__ xs, const u32* __restrict__ rp,
    u64* __restrict__ ex, float* __restrict__ hout) {
    __shared__ alignas(16) u32 hloc[128];    // full h(t-1), f16x2 packed
    __shared__ float zex[4][128];            // gate-major z exchange

    const int bid = blockIdx.x;
    if ((bid & 7) > 1 || (bid >> 3) > 1) return;
    const int dir = bid & 7;
    const int s   = bid >> 3;
    const int tid = threadIdx.x;
    const int g   = tid >> 7;
    const int u_  = tid & 127;
    const int row = g * 256 + s * 128 + u_;

    xs += (size_t)dir * (T_LEN * G4);
    rp += (size_t)dir * DIRSZ;
    u64* exd = ex + dir * (2 * 2 * 64);      // [par][slice][64]

    u32 regw[128];
    {
        const uint4* rp4 = (const uint4*)(rp + (size_t)(s * 512 + tid) * 128);
#pragma unroll
        for (int p = 0; p < 32; ++p) {
            uint4 v = rp4[p];
            regw[4 * p + 0] = v.x; regw[4 * p + 1] = v.y;
            regw[4 * p + 2] = v.z; regw[4 * p + 3] = v.w;
        }
    }
    if (tid < 128) hloc[tid] = 0u;
    float cst0 = 0.f, cst1 = 0.f;
    __syncthreads();

    int tt = dir ? (T_LEN - 1) : 0;
    const int stp = dir ? -1 : 1;
    float xa = xs[(size_t)tt * G4 + row];

    for (int t = 0; t < T_LEN; ++t) {
        float a = xa;
        int tn = (t + 1 < T_LEN) ? tt + stp : tt;
        xa = xs[(size_t)tn * G4 + row];      // prefetch next step (never drained)

        // z[row] = xs[row] + Whh[row,:] . h   (ascending k pairs, one acc)
#pragma unroll
        for (int c = 0; c < 4; ++c) {
            u32 hh[32];
#pragma unroll
            for (int q = 0; q < 8; ++q) {
                uint4 v = *(const uint4*)&hloc[c * 32 + 4 * q];
                hh[4 * q + 0] = v.x; hh[4 * q + 1] = v.y;
                hh[4 * q + 2] = v.z; hh[4 * q + 3] = v.w;
            }
#pragma unroll
            for (int p = 0; p < 32; ++p)
                a = dot2f(regw[c * 32 + p], hh[p], a);
        }

        zex[g][u_] = a;
        step_barrier();

        if (tid < 64) {                       // wave 0: gates for units 2t,2t+1
            float zi0 = zex[0][2 * tid], zi1 = zex[0][2 * tid + 1];
            float zf0 = zex[1][2 * tid], zf1 = zex[1][2 * tid + 1];
            float zg0 = zex[2][2 * tid], zg1 = zex[2][2 * tid + 1];
            float zo0 = zex[3][2 * tid], zo1 = zex[3][2 * tid + 1];

            float si0 = 1.f / (1.f + __expf(-zi0));
            float sf0 = 1.f / (1.f + __expf(-zf0));
            float so0 = 1.f / (1.f + __expf(-zo0));
            float tg0 = 1.f - 2.f / (__expf(2.f * zg0) + 1.f);
            cst0 = sf0 * cst0 + si0 * tg0;
            float th0 = 1.f - 2.f / (__expf(2.f * cst0) + 1.f);
            float hv0 = so0 * th0;

            float si1 = 1.f / (1.f + __expf(-zi1));
            float sf1 = 1.f / (1.f + __expf(-zf1));
            float so1 = 1.f / (1.f + __expf(-zo1));
            float tg1 = 1.f - 2.f / (__expf(2.f * zg1) + 1.f);
            cst1 = sf1 * cst1 + si1 * tg1;
            float th1 = 1.f - 2.f / (__expf(2.f * cst1) + 1.f);
            float hv1 = so1 * th1;

            u32 hp = pack2(hv0, hv1);
            ((u32*)hloc)[s * 64 + tid] = hp;                // own chunk locally
            u64 pay = ((u64)(u32)(t + 1) << 32) | (u64)hp;  // tag | payload
            __hip_atomic_store(&exd[((t & 1) * 2 + s) * 64 + tid], pay,
                               __ATOMIC_RELAXED, __HIP_MEMORY_SCOPE_AGENT);
            float2 hvv; hvv.x = hv0; hvv.y = hv1;
            *(float2*)&hout[(size_t)tt * 512 + dir * 256 + s * 128 + 2 * tid] = hvv;
        } else if (tid < 128) {               // wave 1: poll remote slice
            if (t + 1 < T_LEN) {
                int j  = tid - 64;
                int rs = 1 - s;
                u64 v;
                do {
                    v = __hip_atomic_load(&exd[((t & 1) * 2 + rs) * 64 + j],
                                          __ATOMIC_ACQUIRE,
                                          __HIP_MEMORY_SCOPE_AGENT);
                } while ((u32)(v >> 32) != (u32)(t + 1));
                ((u32*)hloc)[rs * 64 + j] = (u32)v;
            }
        }
        step_barrier();
        tt = tn;
    }
}

// ---------------- launcher ----------------
extern "C" void kernel_launch(void* const* d_in, const int* in_sizes, int n_in,
                              void* d_out, int out_size, void* d_ws, size_t ws_size,
                              hipStream_t stream) {
    const float* x       = (const float*)d_in[0];
    const float* wih_l0f = (const float*)d_in[1];
    const float* whh_l0f = (const float*)d_in[2];
    const float* b_l0f   = (const float*)d_in[3];
    const float* wih_l0b = (const float*)d_in[4];
    const float* whh_l0b = (const float*)d_in[5];
    const float* b_l0b   = (const float*)d_in[6];
    const float* wih_l1f = (const float*)d_in[7];
    const float* whh_l1f = (const float*)d_in[8];
    const float* b_l1f   = (const float*)d_in[9];
    const float* wih_l1b = (const float*)d_in[10];
    const float* whh_l1b = (const float*)d_in[11];
    const float* b_l1b   = (const float*)d_in[12];
    const float* fc1_w   = (const float*)d_in[13];
    const float* fc1_b   = (const float*)d_in[14];
    const float* fc2_w   = (const float*)d_in[15];
    const float* fc2_b   = (const float*)d_in[16];
    float* outp = (float*)d_out;

    char* ws = (char*)d_ws;
    size_t off = 0;
    auto alloc = [&](size_t nbytes) {
        char* p = ws + off;
        off += (nbytes + 255) & ~(size_t)255;
        return p;
    };
    float* xs0   = (float*)alloc((size_t)2 * T_LEN * G4 * 4);
    float* xs1   = (float*)alloc((size_t)2 * T_LEN * G4 * 4);
    float* h1    = (float*)alloc((size_t)T_LEN * 512 * 4);
    float* h2    = (float*)alloc((size_t)T_LEN * 512 * 4);
    float* zb    = (float*)alloc((size_t)T_LEN * 256 * 4);
    float* eb    = (float*)alloc((size_t)T_LEN * 256 * 4);
    float* etb   = (float*)alloc((size_t)T_LEN * 256 * 4);
    float* nrm   = (float*)alloc((size_t)T_LEN * 4);
    float* wt0f  = (float*)alloc((size_t)128 * 1024 * 4);
    float* wt0b  = (float*)alloc((size_t)128 * 1024 * 4);
    float* wt1f  = (float*)alloc((size_t)512 * 1024 * 4);
    float* wt1b  = (float*)alloc((size_t)512 * 1024 * 4);
    float* wtf1  = (float*)alloc((size_t)512 * 256 * 4);
    float* wtf2  = (float*)alloc((size_t)256 * 256 * 4);
    u32*   rpm0  = (u32*)alloc((size_t)2 * DIRSZ * 4);
    u32*   rpm1  = (u32*)alloc((size_t)2 * DIRSZ * 4);
    u64*   exA   = (u64*)alloc((size_t)512 * 8);   // 2 dir x 2 par x 2 sl x 64
    u64*   exB   = (u64*)alloc((size_t)512 * 8);

    // reset exchange tags (every launch / graph replay); exA,exB contiguous
    k_zero<<<8, 256, 0, stream>>>((u32*)exA, 2048);

    // weight transposes
    k_transpose<<<(1024 * 128 + 255) / 256, 256, 0, stream>>>(wih_l0f, wt0f, 1024, 128);
    k_transpose<<<(1024 * 128 + 255) / 256, 256, 0, stream>>>(wih_l0b, wt0b, 1024, 128);
    k_transpose<<<(1024 * 512 + 255) / 256, 256, 0, stream>>>(wih_l1f, wt1f, 1024, 512);
    k_transpose<<<(1024 * 512 + 255) / 256, 256, 0, stream>>>(wih_l1b, wt1b, 1024, 512);
    k_transpose<<<(256 * 512 + 255) / 256, 256, 0, stream>>>(fc1_w, wtf1, 256, 512);
    k_transpose<<<(256 * 256 + 255) / 256, 256, 0, stream>>>(fc2_w, wtf2, 256, 256);

    // recurrent weight packs (per-slice row->thread mapping)
    k_pack_whh_mc<<<512, 256, 0, stream>>>(whh_l0f, rpm0);
    k_pack_whh_mc<<<512, 256, 0, stream>>>(whh_l0b, rpm0 + DIRSZ);
    k_pack_whh_mc<<<512, 256, 0, stream>>>(whh_l1f, rpm1);
    k_pack_whh_mc<<<512, 256, 0, stream>>>(whh_l1b, rpm1 + DIRSZ);

    dim3 g1024(T_LEN / 16, 4);
    // layer 0 input projections
    k_gemm<<<g1024, 256, 0, stream>>>(x, wt0f, b_l0f, nullptr, xs0, T_LEN, 1024, 128, 0);
    k_gemm<<<g1024, 256, 0, stream>>>(x, wt0b, b_l0b, nullptr, xs0 + (size_t)T_LEN * G4, T_LEN, 1024, 128, 0);
    // layer 0 scan (2 dirs x 2 slices on 4 CUs)
    k_scan_mc2<<<16, 512, 0, stream>>>(xs0, rpm0, exA, h1);
    // layer 1 input projections
    k_gemm<<<g1024, 256, 0, stream>>>(h1, wt1f, b_l1f, nullptr, xs1, T_LEN, 1024, 512, 0);
    k_gemm<<<g1024, 256, 0, stream>>>(h1, wt1b, b_l1b, nullptr, xs1 + (size_t)T_LEN * G4, T_LEN, 1024, 512, 0);
    // layer 1 scan
    k_scan_mc2<<<16, 512, 0, stream>>>(xs1, rpm1, exB, h2);
    // FC head
    k_gemm<<<dim3(T_LEN / 16, 1), 256, 0, stream>>>(h2, wtf1, fc1_b, nullptr, zb, T_LEN, 256, 512, 1);
    k_gemm<<<dim3(T_LEN / 16, 1), 256, 0, stream>>>(zb, wtf2, fc2_b, nullptr, eb, T_LEN, 256, 256, 0);
    // cosine-similarity output
    k_transpose<<<(T_LEN * 256 + 255) / 256, 256, 0, stream>>>(eb, etb, T_LEN, 256);
    k_norms<<<T_LEN, 64, 0, stream>>>(eb, nrm);
    k_gemm<<<dim3(T_LEN / 16, T_LEN / 256), 256, 0, stream>>>(eb, etb, nullptr, nrm, outp, T_LEN, T_LEN, 256, 2);
}